// Round 8
// baseline (725.412 us; speedup 1.0000x reference)
//
#include <hip/hip_runtime.h>

#define DEV __device__ __forceinline__

typedef __bf16 bf16x8 __attribute__((ext_vector_type(8)));
typedef float f32x4 __attribute__((ext_vector_type(4)));

DEV float b2f(__bf16 v) { return (float)v; }
DEV __bf16 f2b(float v) { return (__bf16)v; }

// ---------------------------------------------------------------- dtype detect (3-way)
// mode: 0=bf16, 1=f32, 2=f16 (inputs proven f32 on this problem; detector kept
// for robustness -- it is what fixed round 1's NaN).
__global__ void detect_k(const unsigned short* __restrict__ q, int* __restrict__ mode) {
  const int lane = threadIdx.x & 63;
  int cntNaN = 0, cntSmall = 0;
  for (int i = lane; i < 16384; i += 64) {
    const unsigned ef = (q[i] >> 7) & 0xFF;
    if (ef == 0xFF) cntNaN++;
    if (ef < 0x70) cntSmall++;
  }
#pragma unroll
  for (int o = 32; o > 0; o >>= 1) {
    cntNaN += __shfl_down(cntNaN, o);
    cntSmall += __shfl_down(cntSmall, o);
  }
  if (lane == 0) *mode = (cntNaN >= 4) ? 1 : ((cntSmall > 2000) ? 2 : 0);
}

// ---------------------------------------------------------------- convert (mode-aware)
__global__ __launch_bounds__(256) void cvt_k(const void* __restrict__ src,
                                             __bf16* __restrict__ dst,
                                             int n, const int* __restrict__ mode) {
  const int i = blockIdx.x * 256 + threadIdx.x;
  if (i >= n) return;
  const int m = *mode;
  const float v = (m == 1) ? ((const float*)src)[i]
                : (m == 2) ? (float)((const _Float16*)src)[i]
                           : b2f(((const __bf16*)src)[i]);
  dst[i] = f2b(v);
}

// ---------------------------------------------------------------- transpose+convert (1024x1024)
__global__ __launch_bounds__(256) void tnaive_k(const void* __restrict__ in,
                                                __bf16* __restrict__ out,
                                                const int* __restrict__ mode) {
  const int idx = blockIdx.x * 256 + threadIdx.x;  // [0, 1048576)
  const int r = idx >> 10, c = idx & 1023;
  const int m = *mode;
  const float v = (m == 1) ? ((const float*)in)[idx]
                : (m == 2) ? (float)((const _Float16*)in)[idx]
                           : b2f(((const __bf16*)in)[idx]);
  out[(size_t)c * 1024 + r] = f2b(v);
}

// ---------------------------------------------------------------- GEMM (m97 structure; cleared)
// C[M][N] = A[M][K] @ BT[N][K]^T + bias[N]. A,BT bf16 row-major.
template <bool OUT_F32>
__global__ __launch_bounds__(256) void gemm_k(const __bf16* __restrict__ A,
                                              const __bf16* __restrict__ BT,
                                              const __bf16* __restrict__ bias,
                                              void* __restrict__ Cout,
                                              int M, int N, int K) {
  __shared__ __bf16 As[128][72];
  __shared__ __bf16 Bs[128][72];
  const int tid = threadIdx.x, lane = tid & 63, wv = tid >> 6;
  const int quad = lane >> 4, l16 = lane & 15;
  const int m0 = blockIdx.y * 128, n0 = blockIdx.x * 128;
  const int wm = (wv >> 1) * 64, wn = (wv & 1) * 64;
  f32x4 acc[4][4] = {};
  for (int k0 = 0; k0 < K; k0 += 64) {
    for (int i = tid; i < 1024; i += 256) {
      int r = i >> 3, kc = (i & 7) * 8;
      *(int4*)&As[r][kc] = *(const int4*)&A[(size_t)(m0 + r) * K + k0 + kc];
    }
    for (int i = tid; i < 1024; i += 256) {
      int r = i >> 3, kc = (i & 7) * 8;
      *(int4*)&Bs[r][kc] = *(const int4*)&BT[(size_t)(n0 + r) * K + k0 + kc];
    }
    __syncthreads();
#pragma unroll
    for (int ks = 0; ks < 64; ks += 32) {
      const int ka = ks + quad * 8;
      bf16x8 af[4], bfr[4];
#pragma unroll
      for (int i = 0; i < 4; i++) af[i] = *(const bf16x8*)&As[wm + i * 16 + l16][ka];
#pragma unroll
      for (int j = 0; j < 4; j++) bfr[j] = *(const bf16x8*)&Bs[wn + j * 16 + l16][ka];
#pragma unroll
      for (int i = 0; i < 4; i++)
#pragma unroll
        for (int j = 0; j < 4; j++)
          acc[i][j] = __builtin_amdgcn_mfma_f32_16x16x32_bf16(af[i], bfr[j], acc[i][j], 0, 0, 0);
    }
    __syncthreads();
  }
#pragma unroll
  for (int j = 0; j < 4; j++) {
    const int col = n0 + wn + j * 16 + l16;
    const float bv = b2f(bias[col]);
#pragma unroll
    for (int i = 0; i < 4; i++) {
#pragma unroll
      for (int r = 0; r < 4; r++) {
        const int row = m0 + wm + i * 16 + quad * 4 + r;
        const float v = acc[i][j][r] + bv;
        if (OUT_F32)
          ((float*)Cout)[(size_t)row * N + col] = v;  // d_out is FLOAT32 (r7 poke proof)
        else
          ((__bf16*)Cout)[(size_t)row * N + col] = f2b(v);
      }
    }
  }
}

// ---------------------------------------------------------------- LayerNorm (cleared)
__global__ __launch_bounds__(256) void ln_k(const float* __restrict__ Zraw,
                                            const __bf16* __restrict__ g,
                                            const __bf16* __restrict__ bb,
                                            __bf16* __restrict__ Z) {
  __shared__ float red[8];
  const int row = blockIdx.x, tid = threadIdx.x, lane = tid & 63, wv = tid >> 6;
  const float* x = Zraw + (size_t)row * 1024;
  float4 v = *(const float4*)&x[tid * 4];
  float s = v.x + v.y + v.z + v.w;
  float ss = v.x * v.x + v.y * v.y + v.z * v.z + v.w * v.w;
#pragma unroll
  for (int o = 32; o > 0; o >>= 1) {
    s += __shfl_down(s, o);
    ss += __shfl_down(ss, o);
  }
  if (lane == 0) { red[wv] = s; red[4 + wv] = ss; }
  __syncthreads();
  const float S = red[0] + red[1] + red[2] + red[3];
  const float SS = red[4] + red[5] + red[6] + red[7];
  const float mu = S * (1.f / 1024.f);
  const float var = SS * (1.f / 1024.f) - mu * mu;
  const float rstd = rsqrtf(var + 1e-5f);
  const int c = tid * 4;
  float xs[4] = {v.x, v.y, v.z, v.w};
  union { __bf16 h[4]; uint2 u; } pk;
#pragma unroll
  for (int i = 0; i < 4; i++)
    pk.h[i] = f2b((xs[i] - mu) * rstd * b2f(g[c + i]) + b2f(bb[c + i]));
  *(uint2*)&Z[(size_t)row * 1024 + c] = pk.u;
}

// ---------------------------------------------------------------- fast phasor (cleared by r2==r4)
__global__ __launch_bounds__(256) void phasor_k(const __bf16* __restrict__ Qf,
                                                const __bf16* __restrict__ Wphi,
                                                const __bf16* __restrict__ bphi,
                                                __bf16* __restrict__ Qc) {
  __shared__ float w[64][64];
  const int tid = threadIdx.x, lane = tid & 63, wv = tid >> 6;
  for (int i = tid; i < 4096; i += 256) w[i >> 6][i & 63] = b2f(Wphi[i]);
  __syncthreads();
  const float bj = b2f(bphi[lane]);
  const int base = blockIdx.x * 32 + wv * 8;
  for (int rr = 0; rr < 8; rr++) {
    const int row = base + rr;
    const float qj = b2f(Qf[(size_t)row * 64 + lane]);
    float phi = bj;
#pragma unroll 8
    for (int i = 0; i < 64; i++) phi += __shfl(qj, i) * w[i][lane];
    float sn, cs;
    __sincosf(phi, &sn, &cs);
    const size_t ob = (size_t)row * 128;
    Qc[ob + lane] = f2b(qj * cs);
    Qc[ob + 64 + lane] = f2b(qj * sn);
  }
}

// ---------------------------------------------------------------- Hv transpose (cleared)
__global__ __launch_bounds__(256) void hvt_k(const __bf16* __restrict__ Hv,
                                             __bf16* __restrict__ HvT, int S) {
  __shared__ __bf16 t[64][72];
  const int tt = blockIdx.x * 64, h = blockIdx.y, b = blockIdx.z;
  const int tid = threadIdx.x;
  for (int i = tid; i < 512; i += 256) {
    int tok = i >> 3, dc = (i & 7) * 8;
    *(int4*)&t[tok][dc] = *(const int4*)&Hv[((size_t)(b * S + tt + tok) * 16 + h) * 64 + dc];
  }
  __syncthreads();
  for (int i = tid; i < 1024; i += 256) {
    int d = i >> 4, tc = (i & 15) * 4;
    union { __bf16 h4[4]; uint2 u; } pk;
    pk.h4[0] = t[tc + 0][d];
    pk.h4[1] = t[tc + 1][d];
    pk.h4[2] = t[tc + 2][d];
    pk.h4[3] = t[tc + 3][d];
    *(uint2*)&HvT[(((size_t)(b * 16 + h) * 64 + d) * S) + tt + tc] = pk.u;
  }
}

// ---------------------------------------------------------------- flash attention (cleared by r2==r4)
__global__ __launch_bounds__(256) void attn_k(const __bf16* __restrict__ Qc,
                                              const __bf16* __restrict__ Rc,
                                              const __bf16* __restrict__ HvT,
                                              __bf16* __restrict__ Aout, int S) {
  __shared__ __bf16 Qs[128][136];
  __shared__ __bf16 Us[9216];  // union: Rc tile [64][136] / S tile [128][72]
  __shared__ __bf16 Hs[64][72];
  __shared__ float red[256];
  __shared__ float ssrow[128];
  const int tid = threadIdx.x, lane = tid & 63, wv = tid >> 6;
  const int quad = lane >> 4, l16 = lane & 15;
  const int q0 = blockIdx.x * 128, h = blockIdx.y, b = blockIdx.z;

  for (int i = tid; i < 128 * 16; i += 256) {
    int r = i >> 4, cc = (i & 15) * 8;
    *(int4*)&Qs[r][cc] = *(const int4*)&Qc[((size_t)(b * S + q0 + r) * 16 + h) * 128 + cc];
  }
  f32x4 oacc[2][4] = {};
  float ssum = 0.f;
  const size_t hvbase = ((size_t)(b * 16 + h) * 64) * S;

  for (int k0 = 0; k0 < S; k0 += 64) {
    for (int i = tid; i < 64 * 16; i += 256) {
      int r = i >> 4, cc = (i & 15) * 8;
      *(int4*)&Us[r * 136 + cc] = *(const int4*)&Rc[((size_t)(b * S + k0 + r) * 16 + h) * 128 + cc];
    }
    for (int i = tid; i < 512; i += 256) {
      int d = i >> 3, tc = (i & 7) * 8;
      *(int4*)&Hs[d][tc] = *(const int4*)&HvT[hvbase + (size_t)d * S + k0 + tc];
    }
    __syncthreads();
    f32x4 sacc[2][4] = {};
#pragma unroll
    for (int ks = 0; ks < 128; ks += 32) {
      const int ka = ks + quad * 8;
      bf16x8 af[2], bfr[4];
      af[0] = *(const bf16x8*)&Qs[wv * 32 + l16][ka];
      af[1] = *(const bf16x8*)&Qs[wv * 32 + 16 + l16][ka];
#pragma unroll
      for (int j = 0; j < 4; j++) bfr[j] = *(const bf16x8*)&Us[(j * 16 + l16) * 136 + ka];
#pragma unroll
      for (int i = 0; i < 2; i++)
#pragma unroll
        for (int j = 0; j < 4; j++)
          sacc[i][j] = __builtin_amdgcn_mfma_f32_16x16x32_bf16(af[i], bfr[j], sacc[i][j], 0, 0, 0);
    }
    __syncthreads();
#pragma unroll
    for (int i = 0; i < 2; i++)
#pragma unroll
      for (int j = 0; j < 4; j++)
#pragma unroll
        for (int r = 0; r < 4; r++) {
          const int row = wv * 32 + i * 16 + quad * 4 + r, col = j * 16 + l16;
          Us[row * 72 + col] = f2b(sacc[i][j][r]);
        }
    __syncthreads();
    {
      const int r = tid >> 1, cb = (tid & 1) * 32;
      float a = 0.f;
#pragma unroll
      for (int c2 = 0; c2 < 32; c2++) {
        const float v = b2f(Us[r * 72 + cb + c2]);
        a += v * v;
      }
      ssum += a;
    }
#pragma unroll
    for (int ks = 0; ks < 64; ks += 32) {
      const int ka = ks + quad * 8;
      bf16x8 af[2], bfr[4];
      af[0] = *(const bf16x8*)&Us[(wv * 32 + l16) * 72 + ka];
      af[1] = *(const bf16x8*)&Us[(wv * 32 + 16 + l16) * 72 + ka];
#pragma unroll
      for (int j = 0; j < 4; j++) bfr[j] = *(const bf16x8*)&Hs[j * 16 + l16][ka];
#pragma unroll
      for (int i = 0; i < 2; i++)
#pragma unroll
        for (int j = 0; j < 4; j++)
          oacc[i][j] = __builtin_amdgcn_mfma_f32_16x16x32_bf16(af[i], bfr[j], oacc[i][j], 0, 0, 0);
    }
    __syncthreads();
  }
  red[tid] = ssum;
  __syncthreads();
  if (tid < 128) ssrow[tid] = red[2 * tid] + red[2 * tid + 1];
  __syncthreads();
#pragma unroll
  for (int i = 0; i < 2; i++)
#pragma unroll
    for (int j = 0; j < 4; j++)
#pragma unroll
      for (int r = 0; r < 4; r++) {
        const int row = wv * 32 + i * 16 + quad * 4 + r;
        const int col = j * 16 + l16;
        const float nrm = fmaxf(sqrtf(ssrow[row]), 1e-12f);
        const float v = oacc[i][j][r] / nrm;
        Aout[((size_t)(b * S + q0 + row)) * 1024 + h * 64 + col] = f2b(v);
      }
}

// ---------------------------------------------------------------- launch
extern "C" void kernel_launch(void* const* d_in, const int* in_sizes, int n_in,
                              void* d_out, int out_size, void* d_ws, size_t ws_size,
                              hipStream_t stream) {
  const void* query = d_in[0];
  const void* Wz = d_in[3];
  const void* bz = d_in[4];
  const void* ln_g = d_in[5];
  const void* ln_b = d_in[6];
  const void* Wq = d_in[7];
  const void* bq = d_in[8];
  const void* Wr = d_in[9];
  const void* br = d_in[10];
  const void* Wh = d_in[11];
  const void* bh = d_in[12];
  const void* Wphi = d_in[13];
  const void* bphi = d_in[14];
  const void* Wo = d_in[15];
  const void* bo = d_in[16];

  const int n_q = in_sizes[0];   // B*S*1024
  const int Srows = n_q >> 10;   // B*S
  const int S = Srows >> 1;      // B = 2

  char* ws = (char*)d_ws;
  const size_t MB = 1024 * 1024;

  int* mode = (int*)(ws);
  __bf16* sv = (__bf16*)(ws + 4096);
  __bf16* bz_c   = sv + 0 * 4096;
  __bf16* lng_c  = sv + 1 * 4096;
  __bf16* lnb_c  = sv + 2 * 4096;
  __bf16* bq_c   = sv + 3 * 4096;
  __bf16* br_c   = sv + 4 * 4096;
  __bf16* bh_c   = sv + 5 * 4096;
  __bf16* bo_c   = sv + 6 * 4096;
  __bf16* bphi_c = sv + 7 * 4096;
  __bf16* wphi_c = sv + 8 * 4096;
  __bf16* WzT  = (__bf16*)(ws + 1 * MB);
  __bf16* WqT  = (__bf16*)(ws + 3 * MB);
  __bf16* WrT  = (__bf16*)(ws + 5 * MB);
  __bf16* WhT  = (__bf16*)(ws + 7 * MB);
  __bf16* WoT  = (__bf16*)(ws + 9 * MB);
  __bf16* qbf  = (__bf16*)(ws + 11 * MB);  // 8 MB
  float*  Zraw = (float*) (ws + 19 * MB);  // 16 MB, dead after ln
  __bf16* Z    = (__bf16*)(ws + 35 * MB);  // 8 MB, dead after gemm Hv
  __bf16* Qf   = (__bf16*)(ws + 43 * MB);  // 8 MB, dead after phasor Q
  __bf16* Rf   = (__bf16*)(ws + 51 * MB);  // 8 MB, dead after phasor R
  __bf16* Hv   = (__bf16*)(ws + 59 * MB);  // 8 MB, dead after hvt
  __bf16* Qc   = (__bf16*)(ws + 19 * MB);  // 16 MB over dead Zraw
  __bf16* Rc   = (__bf16*)(ws + 67 * MB);  // 16 MB (top 83 MB, proven safe r2/r3)
  __bf16* HvT  = (__bf16*)(ws + 51 * MB);  // 8 MB over dead Rf
  __bf16* Aout = (__bf16*)(ws + 43 * MB);  // 8 MB over dead Qf

  dim3 blk(256);
  detect_k<<<1, 64, 0, stream>>>((const unsigned short*)query, mode);

  cvt_k<<<(n_q + 255) / 256, blk, 0, stream>>>(query, qbf, n_q, mode);
  cvt_k<<<4, blk, 0, stream>>>(bz, bz_c, 1024, mode);
  cvt_k<<<4, blk, 0, stream>>>(ln_g, lng_c, 1024, mode);
  cvt_k<<<4, blk, 0, stream>>>(ln_b, lnb_c, 1024, mode);
  cvt_k<<<4, blk, 0, stream>>>(bq, bq_c, 1024, mode);
  cvt_k<<<4, blk, 0, stream>>>(br, br_c, 1024, mode);
  cvt_k<<<4, blk, 0, stream>>>(bh, bh_c, 1024, mode);
  cvt_k<<<4, blk, 0, stream>>>(bo, bo_c, 1024, mode);
  cvt_k<<<1, blk, 0, stream>>>(bphi, bphi_c, 64, mode);
  cvt_k<<<16, blk, 0, stream>>>(Wphi, wphi_c, 4096, mode);

  tnaive_k<<<4096, blk, 0, stream>>>(Wz, WzT, mode);
  tnaive_k<<<4096, blk, 0, stream>>>(Wq, WqT, mode);
  tnaive_k<<<4096, blk, 0, stream>>>(Wr, WrT, mode);
  tnaive_k<<<4096, blk, 0, stream>>>(Wh, WhT, mode);
  tnaive_k<<<4096, blk, 0, stream>>>(Wo, WoT, mode);

  dim3 ggrid(8, Srows / 128);
  gemm_k<true><<<ggrid, blk, 0, stream>>>(qbf, WzT, bz_c, (void*)Zraw, Srows, 1024, 1024);
  ln_k<<<Srows, blk, 0, stream>>>(Zraw, lng_c, lnb_c, Z);
  gemm_k<false><<<ggrid, blk, 0, stream>>>(Z, WqT, bq_c, (void*)Qf, Srows, 1024, 1024);
  gemm_k<false><<<ggrid, blk, 0, stream>>>(Z, WrT, br_c, (void*)Rf, Srows, 1024, 1024);
  gemm_k<false><<<ggrid, blk, 0, stream>>>(Z, WhT, bh_c, (void*)Hv, Srows, 1024, 1024);
  phasor_k<<<Srows / 2, blk, 0, stream>>>(Qf, wphi_c, bphi_c, Qc);
  phasor_k<<<Srows / 2, blk, 0, stream>>>(Rf, wphi_c, bphi_c, Rc);
  hvt_k<<<dim3(S / 64, 16, 2), blk, 0, stream>>>(Hv, HvT, S);
  attn_k<<<dim3(S / 128, 16, 2), blk, 0, stream>>>(Qc, Rc, HvT, Aout, S);
  // FINAL GEMM WRITES FLOAT32 — d_out is an f32 buffer (round-7 poke proof).
  gemm_k<true><<<ggrid, blk, 0, stream>>>(Aout, WoT, bo_c, d_out, Srows, 1024, 1024);
}

// Round 9
// 593.668 us; speedup vs baseline: 1.2219x; 1.2219x over previous
//
#include <hip/hip_runtime.h>

#define DEV __device__ __forceinline__

typedef __bf16 bf16x8 __attribute__((ext_vector_type(8)));
typedef float f32x4 __attribute__((ext_vector_type(4)));

DEV float b2f(__bf16 v) { return (float)v; }
DEV __bf16 f2b(float v) { return (__bf16)v; }

// ---------------------------------------------------------------- dtype detect (3-way)
__global__ void detect_k(const unsigned short* __restrict__ q, int* __restrict__ mode) {
  const int lane = threadIdx.x & 63;
  int cntNaN = 0, cntSmall = 0;
  for (int i = lane; i < 16384; i += 64) {
    const unsigned ef = (q[i] >> 7) & 0xFF;
    if (ef == 0xFF) cntNaN++;
    if (ef < 0x70) cntSmall++;
  }
#pragma unroll
  for (int o = 32; o > 0; o >>= 1) {
    cntNaN += __shfl_down(cntNaN, o);
    cntSmall += __shfl_down(cntSmall, o);
  }
  if (lane == 0) *mode = (cntNaN >= 4) ? 1 : ((cntSmall > 2000) ? 2 : 0);
}

// ---------------------------------------------------------------- convert (mode-aware)
__global__ __launch_bounds__(256) void cvt_k(const void* __restrict__ src,
                                             __bf16* __restrict__ dst,
                                             int n, const int* __restrict__ mode) {
  const int i = blockIdx.x * 256 + threadIdx.x;
  if (i >= n) return;
  const int m = *mode;
  const float v = (m == 1) ? ((const float*)src)[i]
                : (m == 2) ? (float)((const _Float16*)src)[i]
                           : b2f(((const __bf16*)src)[i]);
  dst[i] = f2b(v);
}

// ---------------------------------------------------------------- LDS-tiled transpose+convert
// out[c][r] = bf16(in[r][c]) for 1024x1024. 64x64 tiles (r2-verified structure).
__global__ __launch_bounds__(256) void tcvt_k(const void* __restrict__ in,
                                              __bf16* __restrict__ out,
                                              const int* __restrict__ mode) {
  __shared__ __bf16 tile[64][68];
  const int c0 = blockIdx.x * 64, r0 = blockIdx.y * 64;
  const int tid = threadIdx.x;
  const int m = *mode;
  for (int i = tid; i < 64 * 16; i += 256) {
    int r = i >> 4, cc = (i & 15) * 4;
    const size_t base = (size_t)(r0 + r) * 1024 + c0 + cc;
    if (m == 1) {
      float4 v = *(const float4*)((const float*)in + base);
      tile[r][cc + 0] = f2b(v.x);
      tile[r][cc + 1] = f2b(v.y);
      tile[r][cc + 2] = f2b(v.z);
      tile[r][cc + 3] = f2b(v.w);
    } else if (m == 2) {
      const _Float16* p = (const _Float16*)in + base;
      tile[r][cc + 0] = f2b((float)p[0]);
      tile[r][cc + 1] = f2b((float)p[1]);
      tile[r][cc + 2] = f2b((float)p[2]);
      tile[r][cc + 3] = f2b((float)p[3]);
    } else {
      *(uint2*)&tile[r][cc] = *(const uint2*)((const __bf16*)in + base);
    }
  }
  __syncthreads();
  for (int i = tid; i < 64 * 16; i += 256) {
    int c = i >> 4, rr = (i & 15) * 4;
    union { __bf16 h[4]; uint2 u; } pk;
    pk.h[0] = tile[rr + 0][c];
    pk.h[1] = tile[rr + 1][c];
    pk.h[2] = tile[rr + 2][c];
    pk.h[3] = tile[rr + 3][c];
    *(uint2*)&out[(size_t)(c0 + c) * 1024 + r0 + rr] = pk.u;
  }
}

// ---------------------------------------------------------------- GEMM (m97 structure; verified)
// C[M][N] = A[M][K] @ BT[N][K]^T + bias[N]. A bf16 unless A_CHK (mode-aware staging convert).
template <bool OUT_F32, bool A_CHK>
__global__ __launch_bounds__(256) void gemm_k(const void* __restrict__ Av,
                                              const __bf16* __restrict__ BT,
                                              const __bf16* __restrict__ bias,
                                              void* __restrict__ Cout,
                                              int M, int N, int K,
                                              const int* __restrict__ mode) {
  __shared__ __bf16 As[128][72];
  __shared__ __bf16 Bs[128][72];
  const int tid = threadIdx.x, lane = tid & 63, wv = tid >> 6;
  const int quad = lane >> 4, l16 = lane & 15;
  const int m0 = blockIdx.y * 128, n0 = blockIdx.x * 128;
  const int wm = (wv >> 1) * 64, wn = (wv & 1) * 64;
  int am = 0;
  if constexpr (A_CHK) am = *mode;
  f32x4 acc[4][4] = {};
  for (int k0 = 0; k0 < K; k0 += 64) {
    if (A_CHK && am == 1) {
      for (int i = tid; i < 1024; i += 256) {
        int r = i >> 3, kc = (i & 7) * 8;
        const float* ap = (const float*)Av + (size_t)(m0 + r) * K + k0 + kc;
        float4 v0 = *(const float4*)ap, v1 = *(const float4*)(ap + 4);
        union { __bf16 h[8]; int4 u; } pk;
        pk.h[0] = f2b(v0.x); pk.h[1] = f2b(v0.y); pk.h[2] = f2b(v0.z); pk.h[3] = f2b(v0.w);
        pk.h[4] = f2b(v1.x); pk.h[5] = f2b(v1.y); pk.h[6] = f2b(v1.z); pk.h[7] = f2b(v1.w);
        *(int4*)&As[r][kc] = pk.u;
      }
    } else if (A_CHK && am == 2) {
      for (int i = tid; i < 1024; i += 256) {
        int r = i >> 3, kc = (i & 7) * 8;
        const _Float16* ap = (const _Float16*)Av + (size_t)(m0 + r) * K + k0 + kc;
        union { __bf16 h[8]; int4 u; } pk;
#pragma unroll
        for (int t = 0; t < 8; t++) pk.h[t] = f2b((float)ap[t]);
        *(int4*)&As[r][kc] = pk.u;
      }
    } else {
      for (int i = tid; i < 1024; i += 256) {
        int r = i >> 3, kc = (i & 7) * 8;
        *(int4*)&As[r][kc] = *(const int4*)((const __bf16*)Av + (size_t)(m0 + r) * K + k0 + kc);
      }
    }
    for (int i = tid; i < 1024; i += 256) {
      int r = i >> 3, kc = (i & 7) * 8;
      *(int4*)&Bs[r][kc] = *(const int4*)&BT[(size_t)(n0 + r) * K + k0 + kc];
    }
    __syncthreads();
#pragma unroll
    for (int ks = 0; ks < 64; ks += 32) {
      const int ka = ks + quad * 8;
      bf16x8 af[4], bfr[4];
#pragma unroll
      for (int i = 0; i < 4; i++) af[i] = *(const bf16x8*)&As[wm + i * 16 + l16][ka];
#pragma unroll
      for (int j = 0; j < 4; j++) bfr[j] = *(const bf16x8*)&Bs[wn + j * 16 + l16][ka];
#pragma unroll
      for (int i = 0; i < 4; i++)
#pragma unroll
        for (int j = 0; j < 4; j++)
          acc[i][j] = __builtin_amdgcn_mfma_f32_16x16x32_bf16(af[i], bfr[j], acc[i][j], 0, 0, 0);
    }
    __syncthreads();
  }
#pragma unroll
  for (int j = 0; j < 4; j++) {
    const int col = n0 + wn + j * 16 + l16;
    const float bv = b2f(bias[col]);
#pragma unroll
    for (int i = 0; i < 4; i++) {
#pragma unroll
      for (int r = 0; r < 4; r++) {
        const int row = m0 + wm + i * 16 + quad * 4 + r;
        const float v = acc[i][j][r] + bv;
        if (OUT_F32)
          ((float*)Cout)[(size_t)row * N + col] = v;
        else
          ((__bf16*)Cout)[(size_t)row * N + col] = f2b(v);
      }
    }
  }
}

// ---------------------------------------------------------------- fused Q/R/H GEMM
// BT3 = [3072][1024] (WqT|WrT|WhT stacked), bias3[3072]. K=N=1024 per output.
__global__ __launch_bounds__(256) void qrh_gemm_k(const __bf16* __restrict__ A,
                                                  const __bf16* __restrict__ BT3,
                                                  const __bf16* __restrict__ bias3,
                                                  __bf16* __restrict__ Qf,
                                                  __bf16* __restrict__ Rf,
                                                  __bf16* __restrict__ Hv,
                                                  int M) {
  __shared__ __bf16 As[128][72];
  __shared__ __bf16 Bs[128][72];
  const int tid = threadIdx.x, lane = tid & 63, wv = tid >> 6;
  const int quad = lane >> 4, l16 = lane & 15;
  const int m0 = blockIdx.y * 128, n0g = blockIdx.x * 128;
  const int which = n0g >> 10, n0 = n0g & 1023;
  __bf16* out = (which == 0) ? Qf : (which == 1) ? Rf : Hv;
  const int wm = (wv >> 1) * 64, wn = (wv & 1) * 64;
  f32x4 acc[4][4] = {};
  for (int k0 = 0; k0 < 1024; k0 += 64) {
    for (int i = tid; i < 1024; i += 256) {
      int r = i >> 3, kc = (i & 7) * 8;
      *(int4*)&As[r][kc] = *(const int4*)&A[(size_t)(m0 + r) * 1024 + k0 + kc];
    }
    for (int i = tid; i < 1024; i += 256) {
      int r = i >> 3, kc = (i & 7) * 8;
      *(int4*)&Bs[r][kc] = *(const int4*)&BT3[(size_t)(n0g + r) * 1024 + k0 + kc];
    }
    __syncthreads();
#pragma unroll
    for (int ks = 0; ks < 64; ks += 32) {
      const int ka = ks + quad * 8;
      bf16x8 af[4], bfr[4];
#pragma unroll
      for (int i = 0; i < 4; i++) af[i] = *(const bf16x8*)&As[wm + i * 16 + l16][ka];
#pragma unroll
      for (int j = 0; j < 4; j++) bfr[j] = *(const bf16x8*)&Bs[wn + j * 16 + l16][ka];
#pragma unroll
      for (int i = 0; i < 4; i++)
#pragma unroll
        for (int j = 0; j < 4; j++)
          acc[i][j] = __builtin_amdgcn_mfma_f32_16x16x32_bf16(af[i], bfr[j], acc[i][j], 0, 0, 0);
    }
    __syncthreads();
  }
#pragma unroll
  for (int j = 0; j < 4; j++) {
    const int colg = n0g + wn + j * 16 + l16;
    const int col = n0 + wn + j * 16 + l16;
    const float bv = b2f(bias3[colg]);
#pragma unroll
    for (int i = 0; i < 4; i++) {
#pragma unroll
      for (int r = 0; r < 4; r++) {
        const int row = m0 + wm + i * 16 + quad * 4 + r;
        out[(size_t)row * 1024 + col] = f2b(acc[i][j][r] + bv);
      }
    }
  }
}

// ---------------------------------------------------------------- LayerNorm (cleared)
__global__ __launch_bounds__(256) void ln_k(const float* __restrict__ Zraw,
                                            const __bf16* __restrict__ g,
                                            const __bf16* __restrict__ bb,
                                            __bf16* __restrict__ Z) {
  __shared__ float red[8];
  const int row = blockIdx.x, tid = threadIdx.x, lane = tid & 63, wv = tid >> 6;
  const float* x = Zraw + (size_t)row * 1024;
  float4 v = *(const float4*)&x[tid * 4];
  float s = v.x + v.y + v.z + v.w;
  float ss = v.x * v.x + v.y * v.y + v.z * v.z + v.w * v.w;
#pragma unroll
  for (int o = 32; o > 0; o >>= 1) {
    s += __shfl_down(s, o);
    ss += __shfl_down(ss, o);
  }
  if (lane == 0) { red[wv] = s; red[4 + wv] = ss; }
  __syncthreads();
  const float S = red[0] + red[1] + red[2] + red[3];
  const float SS = red[4] + red[5] + red[6] + red[7];
  const float mu = S * (1.f / 1024.f);
  const float var = SS * (1.f / 1024.f) - mu * mu;
  const float rstd = rsqrtf(var + 1e-5f);
  const int c = tid * 4;
  float xs[4] = {v.x, v.y, v.z, v.w};
  union { __bf16 h[4]; uint2 u; } pk;
#pragma unroll
  for (int i = 0; i < 4; i++)
    pk.h[i] = f2b((xs[i] - mu) * rstd * b2f(g[c + i]) + b2f(bb[c + i]));
  *(uint2*)&Z[(size_t)row * 1024 + c] = pk.u;
}

// ---------------------------------------------------------------- fast phasor (cleared)
__global__ __launch_bounds__(256) void phasor_k(const __bf16* __restrict__ Qf,
                                                const __bf16* __restrict__ Wphi,
                                                const __bf16* __restrict__ bphi,
                                                __bf16* __restrict__ Qc) {
  __shared__ float w[64][64];
  const int tid = threadIdx.x, lane = tid & 63, wv = tid >> 6;
  for (int i = tid; i < 4096; i += 256) w[i >> 6][i & 63] = b2f(Wphi[i]);
  __syncthreads();
  const float bj = b2f(bphi[lane]);
  const int base = blockIdx.x * 32 + wv * 8;
  for (int rr = 0; rr < 8; rr++) {
    const int row = base + rr;
    const float qj = b2f(Qf[(size_t)row * 64 + lane]);
    float phi = bj;
#pragma unroll 8
    for (int i = 0; i < 64; i++) phi += __shfl(qj, i) * w[i][lane];
    float sn, cs;
    __sincosf(phi, &sn, &cs);
    const size_t ob = (size_t)row * 128;
    Qc[ob + lane] = f2b(qj * cs);
    Qc[ob + 64 + lane] = f2b(qj * sn);
  }
}

// ---------------------------------------------------------------- Hv transpose (cleared)
__global__ __launch_bounds__(256) void hvt_k(const __bf16* __restrict__ Hv,
                                             __bf16* __restrict__ HvT, int S) {
  __shared__ __bf16 t[64][72];
  const int tt = blockIdx.x * 64, h = blockIdx.y, b = blockIdx.z;
  const int tid = threadIdx.x;
  for (int i = tid; i < 512; i += 256) {
    int tok = i >> 3, dc = (i & 7) * 8;
    *(int4*)&t[tok][dc] = *(const int4*)&Hv[((size_t)(b * S + tt + tok) * 16 + h) * 64 + dc];
  }
  __syncthreads();
  for (int i = tid; i < 1024; i += 256) {
    int d = i >> 4, tc = (i & 15) * 4;
    union { __bf16 h4[4]; uint2 u; } pk;
    pk.h4[0] = t[tc + 0][d];
    pk.h4[1] = t[tc + 1][d];
    pk.h4[2] = t[tc + 2][d];
    pk.h4[3] = t[tc + 3][d];
    *(uint2*)&HvT[(((size_t)(b * 16 + h) * 64 + d) * S) + tt + tc] = pk.u;
  }
}

// ---------------------------------------------------------------- flash attention v2
// v2: Q-frags hoisted to regs; ssum from f32 regs (+shfl_xor butterfly);
// XOR-swizzled S tile (col-group ^= (row>>2)&7) -> 2-way max bank aliasing.
__global__ __launch_bounds__(256) void attn_k(const __bf16* __restrict__ Qc,
                                              const __bf16* __restrict__ Rc,
                                              const __bf16* __restrict__ HvT,
                                              __bf16* __restrict__ Aout, int S) {
  __shared__ __bf16 Qs[128][136];  // 34816 B
  __shared__ __bf16 Us[9216];      // union: Rc tile [64][136] / swizzled S tile [128][72]
  __shared__ __bf16 Hs[64][72];    // 9216 B -> total 62464 B
  const int tid = threadIdx.x, lane = tid & 63, wv = tid >> 6;
  const int quad = lane >> 4, l16 = lane & 15;
  const int q0 = blockIdx.x * 128, h = blockIdx.y, b = blockIdx.z;

  for (int i = tid; i < 128 * 16; i += 256) {
    int r = i >> 4, cc = (i & 15) * 8;
    *(int4*)&Qs[r][cc] = *(const int4*)&Qc[((size_t)(b * S + q0 + r) * 16 + h) * 128 + cc];
  }
  __syncthreads();
  // hoist Q fragments (A-layout: row = wv*32+i*16+l16, k = s*32+quad*8)
  bf16x8 qf[2][4];
#pragma unroll
  for (int i = 0; i < 2; i++)
#pragma unroll
    for (int s = 0; s < 4; s++)
      qf[i][s] = *(const bf16x8*)&Qs[wv * 32 + i * 16 + l16][s * 32 + quad * 8];

  f32x4 oacc[2][4] = {};
  float rssq[8] = {};  // per-lane partial sum-of-squares for rows wv*32+i*16+quad*4+r
  const size_t hvbase = ((size_t)(b * 16 + h) * 64) * S;

  for (int k0 = 0; k0 < S; k0 += 64) {
    for (int i = tid; i < 64 * 16; i += 256) {
      int r = i >> 4, cc = (i & 15) * 8;
      *(int4*)&Us[r * 136 + cc] = *(const int4*)&Rc[((size_t)(b * S + k0 + r) * 16 + h) * 128 + cc];
    }
    for (int i = tid; i < 512; i += 256) {
      int d = i >> 3, tc = (i & 7) * 8;
      *(int4*)&Hs[d][tc] = *(const int4*)&HvT[hvbase + (size_t)d * S + k0 + tc];
    }
    __syncthreads();
    f32x4 sacc[2][4] = {};
#pragma unroll
    for (int s = 0; s < 4; s++) {
      const int ka = s * 32 + quad * 8;
      bf16x8 bfr[4];
#pragma unroll
      for (int j = 0; j < 4; j++) bfr[j] = *(const bf16x8*)&Us[(j * 16 + l16) * 136 + ka];
#pragma unroll
      for (int i = 0; i < 2; i++)
#pragma unroll
        for (int j = 0; j < 4; j++)
          sacc[i][j] = __builtin_amdgcn_mfma_f32_16x16x32_bf16(qf[i][s], bfr[j], sacc[i][j], 0, 0, 0);
    }
    __syncthreads();  // Rc-tile reads done before S overwrite
    // ssq from exact f32 scores (register-side; no LDS pass)
#pragma unroll
    for (int i = 0; i < 2; i++)
#pragma unroll
      for (int j = 0; j < 4; j++)
#pragma unroll
        for (int r = 0; r < 4; r++)
          rssq[i * 4 + r] += sacc[i][j][r] * sacc[i][j][r];
    // swizzled S store: element (row, col) -> row*72 + (g ^ ((row>>2)&7))*8 + (col&7)
#pragma unroll
    for (int i = 0; i < 2; i++)
#pragma unroll
      for (int j = 0; j < 4; j++) {
        const int g = j * 2 + (l16 >> 3), o = l16 & 7;
#pragma unroll
        for (int r = 0; r < 4; r++) {
          const int row = wv * 32 + i * 16 + quad * 4 + r;
          Us[row * 72 + ((g ^ ((row >> 2) & 7)) << 3) + o] = f2b(sacc[i][j][r]);
        }
      }
    __syncthreads();
    // PV: O += S @ Hv^T-staged
#pragma unroll
    for (int s2 = 0; s2 < 2; s2++) {
      const int gk = s2 * 4 + quad;  // k-group index
      bf16x8 af[2], bfr[4];
#pragma unroll
      for (int i = 0; i < 2; i++) {
        const int row = wv * 32 + i * 16 + l16;
        af[i] = *(const bf16x8*)&Us[row * 72 + ((gk ^ ((row >> 2) & 7)) << 3)];
      }
#pragma unroll
      for (int j = 0; j < 4; j++) bfr[j] = *(const bf16x8*)&Hs[j * 16 + l16][s2 * 32 + quad * 8];
#pragma unroll
      for (int i = 0; i < 2; i++)
#pragma unroll
        for (int j = 0; j < 4; j++)
          oacc[i][j] = __builtin_amdgcn_mfma_f32_16x16x32_bf16(af[i], bfr[j], oacc[i][j], 0, 0, 0);
    }
    __syncthreads();  // S reads done before next Rc staging
  }
  // reduce rssq across the 16 col-lanes (lanes sharing quad have identical row sets)
#pragma unroll
  for (int off = 1; off < 16; off <<= 1)
#pragma unroll
    for (int t = 0; t < 8; t++) rssq[t] += __shfl_xor(rssq[t], off);
#pragma unroll
  for (int i = 0; i < 2; i++)
#pragma unroll
    for (int j = 0; j < 4; j++)
#pragma unroll
      for (int r = 0; r < 4; r++) {
        const int row = wv * 32 + i * 16 + quad * 4 + r;
        const int col = j * 16 + l16;
        const float nrm = fmaxf(sqrtf(rssq[i * 4 + r]), 1e-12f);
        Aout[((size_t)(b * S + q0 + row)) * 1024 + h * 64 + col] = f2b(oacc[i][j][r] / nrm);
      }
}

// ---------------------------------------------------------------- launch
extern "C" void kernel_launch(void* const* d_in, const int* in_sizes, int n_in,
                              void* d_out, int out_size, void* d_ws, size_t ws_size,
                              hipStream_t stream) {
  const void* query = d_in[0];
  const void* Wz = d_in[3];
  const void* bz = d_in[4];
  const void* ln_g = d_in[5];
  const void* ln_b = d_in[6];
  const void* Wq = d_in[7];
  const void* bq = d_in[8];
  const void* Wr = d_in[9];
  const void* br = d_in[10];
  const void* Wh = d_in[11];
  const void* bh = d_in[12];
  const void* Wphi = d_in[13];
  const void* bphi = d_in[14];
  const void* Wo = d_in[15];
  const void* bo = d_in[16];

  const int n_q = in_sizes[0];   // B*S*1024
  const int Srows = n_q >> 10;   // B*S
  const int S = Srows >> 1;      // B = 2

  char* ws = (char*)d_ws;
  const size_t MB = 1024 * 1024;

  int* mode = (int*)(ws);
  __bf16* sv = (__bf16*)(ws + 4096);
  __bf16* bz_c   = sv + 0 * 4096;
  __bf16* lng_c  = sv + 1 * 4096;
  __bf16* lnb_c  = sv + 2 * 4096;
  __bf16* bo_c   = sv + 3 * 4096;
  __bf16* bphi_c = sv + 4 * 4096;
  __bf16* wphi_c = sv + 5 * 4096;   // 4096 elems
  __bf16* bqrh   = sv + 6 * 4096;   // 3072 elems
  __bf16* WzT    = (__bf16*)(ws + 1 * MB);   // 2 MB
  __bf16* WoT    = (__bf16*)(ws + 3 * MB);   // 2 MB
  __bf16* WqrhT  = (__bf16*)(ws + 5 * MB);   // 6 MB (Wq|Wr|Wh transposed, stacked)
  float*  Zraw   = (float*) (ws + 11 * MB);  // 16 MB, dead after ln
  __bf16* Z      = (__bf16*)(ws + 27 * MB);  // 8 MB, dead after qrh gemm
  __bf16* Qf     = (__bf16*)(ws + 35 * MB);  // 8 MB, dead after phasor Q
  __bf16* Rf     = (__bf16*)(ws + 43 * MB);  // 8 MB, dead after phasor R
  __bf16* Hv     = (__bf16*)(ws + 51 * MB);  // 8 MB, dead after hvt
  __bf16* Rc     = (__bf16*)(ws + 59 * MB);  // 16 MB (top = 75 MB, proven safe)
  __bf16* Qc     = (__bf16*)(ws + 11 * MB);  // 16 MB over dead Zraw
  __bf16* HvT    = (__bf16*)(ws + 27 * MB);  // 8 MB over dead Z
  __bf16* Aout   = (__bf16*)(ws + 35 * MB);  // 8 MB over dead Qf

  dim3 blk(256);
  detect_k<<<1, 64, 0, stream>>>((const unsigned short*)query, mode);

  cvt_k<<<4, blk, 0, stream>>>(bz, bz_c, 1024, mode);
  cvt_k<<<4, blk, 0, stream>>>(ln_g, lng_c, 1024, mode);
  cvt_k<<<4, blk, 0, stream>>>(ln_b, lnb_c, 1024, mode);
  cvt_k<<<4, blk, 0, stream>>>(bo, bo_c, 1024, mode);
  cvt_k<<<1, blk, 0, stream>>>(bphi, bphi_c, 64, mode);
  cvt_k<<<16, blk, 0, stream>>>(Wphi, wphi_c, 4096, mode);
  cvt_k<<<4, blk, 0, stream>>>(bq, bqrh, 1024, mode);
  cvt_k<<<4, blk, 0, stream>>>(br, bqrh + 1024, 1024, mode);
  cvt_k<<<4, blk, 0, stream>>>(bh, bqrh + 2048, 1024, mode);

  dim3 tgrid(16, 16);
  tcvt_k<<<tgrid, blk, 0, stream>>>(Wz, WzT, mode);
  tcvt_k<<<tgrid, blk, 0, stream>>>(Wo, WoT, mode);
  tcvt_k<<<tgrid, blk, 0, stream>>>(Wq, WqrhT, mode);
  tcvt_k<<<tgrid, blk, 0, stream>>>(Wr, WqrhT + 1024 * 1024, mode);
  tcvt_k<<<tgrid, blk, 0, stream>>>(Wh, WqrhT + 2 * 1024 * 1024, mode);

  dim3 ggrid(8, Srows / 128);
  gemm_k<true, true><<<ggrid, blk, 0, stream>>>(query, WzT, bz_c, (void*)Zraw,
                                                Srows, 1024, 1024, mode);
  ln_k<<<Srows, blk, 0, stream>>>(Zraw, lng_c, lnb_c, Z);
  qrh_gemm_k<<<dim3(24, Srows / 128), blk, 0, stream>>>(Z, WqrhT, bqrh, Qf, Rf, Hv, Srows);
  phasor_k<<<Srows / 2, blk, 0, stream>>>(Qf, wphi_c, bphi_c, Qc);
  phasor_k<<<Srows / 2, blk, 0, stream>>>(Rf, wphi_c, bphi_c, Rc);
  hvt_k<<<dim3(S / 64, 16, 2), blk, 0, stream>>>(Hv, HvT, S);
  attn_k<<<dim3(S / 128, 16, 2), blk, 0, stream>>>(Qc, Rc, HvT, Aout, S);
  gemm_k<true, false><<<ggrid, blk, 0, stream>>>(Aout, WoT, bo_c, d_out,
                                                 Srows, 1024, 1024, mode);
}